// Round 10
// baseline (25.869 us; speedup 1.0000x reference)
//
#include <hip/hip_runtime.h>

#define IMG_H 512
#define IMG_W 512
#define NB    8
#define TILE_R 16
#define TILE_C 32
#define LROWS (TILE_R + 2)          // 18: owner rows + 2 halo rows below
#define LCOLS (TILE_C + 4)          // 36: owner col j -> lds col j+2
#define NELEM (LROWS * LCOLS)       // 648
#define TPR   (IMG_W / TILE_C)      // 16
#define TPI   ((IMG_H / TILE_R) * TPR)  // 512
#define NBLK  (NB * TPI)            // 4096 -> 2 generations per CU
#define N_MEAN 16777216.0           // B * 8 dirs * H * W
#define LOG2E 1.44269504f
#define LN2   0.69314718f

__device__ __forceinline__ float frcp(float x){ return __builtin_amdgcn_rcpf(x); }
__device__ __forceinline__ float fexp2(float x){ return __builtin_amdgcn_exp2f(x); }
__device__ __forceinline__ float flog2(float x){ return __builtin_amdgcn_logf(x); }

// Per-pixel pack {s, mw, e', nw}:
//   s  = sigmoid(c_map)
//   mw = (t ? -0.6 : -1.4) * log(sel+1e-4), sel = t ? s : 1-s   (eq-pair num, K=1 weight)
//   e' = (t ? -1 : +1) * exp(-s);  e' == 0  => OOB sentinel
//   nw = (t ? -0.07 : -0.28) * log(sel+1e-4)                    (nbr num, -0.35*k folded)
__device__ __forceinline__ float4 make_pack(float x, int t_, bool ok) {
    if (!ok) return make_float4(0.0f, 0.0f, 0.0f, 0.0f);
    bool  t = t_ != 0;
    float s   = frcp(1.0f + fexp2(x * -LOG2E));
    float sel = t ? s : (1.0f - s);
    float L   = LN2 * flog2(sel + 1e-4f);
    float e   = fexp2(s * -LOG2E);
    return make_float4(s, (t ? -0.6f : -1.4f) * L, t ? -e : e,
                       (t ? -0.07f : -0.28f) * L);
}

__global__ __launch_bounds__(256, 8) void scloss_main(
    const float* __restrict__ cmap, const int* __restrict__ tgt,
    float* __restrict__ partials)
{
    __shared__ float4 pack[NELEM];

    int blk = blockIdx.x;
    int b   = blk / TPI;
    int ti  = blk % TPI;
    int tr  = (ti / TPR) * TILE_R;
    int tc  = (ti % TPR) * TILE_C;

    const float* cimg = cmap + (size_t)b * (IMG_H * IMG_W);
    const int*   timg = tgt  + (size_t)b * (IMG_H * IMG_W);

    // Stage rows tr..tr+17, cols tc-2..tc+33. All global loads hoisted and
    // issued back-to-back (predicated) -> one HBM-latency exposure.
    {
        const int idx0 = threadIdx.x, idx1 = idx0 + 256, idx2 = idx0 + 512;
        int lr0 = idx0 / LCOLS, lc0 = idx0 - lr0 * LCOLS;
        int lr1 = idx1 / LCOLS, lc1 = idx1 - lr1 * LCOLS;
        int lr2 = idx2 / LCOLS, lc2 = idx2 - lr2 * LCOLS;
        int gr0 = tr + lr0, gc0 = tc + lc0 - 2;
        int gr1 = tr + lr1, gc1 = tc + lc1 - 2;
        int gr2 = tr + lr2, gc2 = tc + lc2 - 2;
        bool ok0 = (gr0 < IMG_H) && ((unsigned)gc0 < (unsigned)IMG_W);
        bool ok1 = (gr1 < IMG_H) && ((unsigned)gc1 < (unsigned)IMG_W);
        bool in2 = idx2 < NELEM;
        bool ok2 = in2 && (gr2 < IMG_H) && ((unsigned)gc2 < (unsigned)IMG_W);
        float c0 = 0.0f, c1 = 0.0f, c2 = 0.0f;
        int   t0 = 0,    t1 = 0,    t2 = 0;
        if (ok0) { int o = gr0 * IMG_W + gc0; c0 = cimg[o]; t0 = timg[o]; }
        if (ok1) { int o = gr1 * IMG_W + gc1; c1 = cimg[o]; t1 = timg[o]; }
        if (ok2) { int o = gr2 * IMG_W + gc2; c2 = cimg[o]; t2 = timg[o]; }
        pack[idx0] = make_pack(c0, t0, ok0);
        pack[idx1] = make_pack(c1, t1, ok1);
        if (in2) pack[idx2] = make_pack(c2, t2, ok2);
    }
    __syncthreads();

    int j  = threadIdx.x & 31;
    int i0 = threadIdx.x >> 5;      // 0..7 -> owner rows 2*i0, 2*i0+1
    float acc = 0.0f;

// One edge on a pre-loaded neighbor float4 (vb), named-scalar outputs only.
#define EDGE(VB, Dd, Nn, WSK, MK) do {                                    \
        float4 vb  = (VB);                                                \
        bool  tb   = vb.z < 0.0f;                                         \
        bool  qpos = (ta == tb);           /* both targets equal */       \
        bool  qnz  = vb.z != 0.0f;         /* neighbor in bounds */       \
        float ppp  = __builtin_fmaf(sa, vb.x, 1e-4f);                     \
        float ompp = __builtin_fmaf(-sa, vb.x, 1.0001f);                  \
        float argc = (qpos && ta) ? ppp : ompp;                           \
        float lg   = flog2(argc);                                         \
        float E    = fexp2(__builtin_fmaf(ppp, -LOG2E, 1e-4f * LOG2E));   \
        float een  = ta ? vb.z : epa;      /* e' of the t=0 endpoint */   \
        float ee   = qpos ? E : een;                                      \
        Dd         = __builtin_fmaf(-LN2, lg, ee);                        \
        float nm   = qpos ? __builtin_fmaf(WSK, vb.y, MK) : (nwa + vb.w); \
        Nn         = qnz ? nm : 0.0f;                                     \
    } while (0)

// 4 divisions with one reciprocal.
#define COMBINE do {                                                      \
        float d01 = D0 * D1, d23 = D2 * D3;                               \
        float R   = frcp(d01 * d23);                                      \
        float n01 = __builtin_fmaf(N1, D0, N0 * D1);                      \
        float n23 = __builtin_fmaf(N3, D2, N2 * D3);                      \
        acc = __builtin_fmaf(__builtin_fmaf(n23, d01, n01 * d23), R, acc);\
    } while (0)

// One pixel: 8 edges (E,SE,S,SW at K=1,2).
#define PIXEL(VA, S1X, S2X, base) do {                                    \
        float4 va_  = (VA);                                               \
        bool  ta  = va_.z < 0.0f;                                         \
        float sa  = va_.x, nwa = va_.w, epa = va_.z;                      \
        float mwa = va_.y, hmw = 0.5f * va_.y;                            \
        float D0, D1, D2, D3, N0, N1, N2, N3;                             \
        EDGE(base[1],           D0, N0, 1.0f, mwa);   /* E  K1 */         \
        EDGE(base[LCOLS + 1],   D1, N1, 1.0f, mwa);   /* SE K1 */         \
        EDGE(S1X,               D2, N2, 1.0f, mwa);   /* S  K1 */         \
        EDGE(base[LCOLS - 1],   D3, N3, 1.0f, mwa);   /* SW K1 */         \
        COMBINE;                                                          \
        EDGE(base[2],           D0, N0, 0.5f, hmw);   /* E  K2 */         \
        EDGE(base[2*LCOLS + 2], D1, N1, 0.5f, hmw);   /* SE K2 */         \
        EDGE(S2X,               D2, N2, 0.5f, hmw);   /* S  K2 */         \
        EDGE(base[2*LCOLS - 2], D3, N3, 0.5f, hmw);   /* SW K2 */         \
        COMBINE;                                                          \
    } while (0)

    {
        const float4* b0 = &pack[(2 * i0) * LCOLS + (j + 2)];
        const float4* b1 = b0 + LCOLS;
        float4 va0 = b0[0], va1 = b1[0];
        PIXEL(va0, va1, b0[2 * LCOLS], b0);
        PIXEL(va1, b1[LCOLS], b1[2 * LCOLS], b1);
    }
#undef PIXEL
#undef COMBINE
#undef EDGE

    // Block reduction: wave64 shuffle then cross-wave via LDS.
    #pragma unroll
    for (int o = 32; o > 0; o >>= 1) acc += __shfl_down(acc, o, 64);
    __shared__ float wsum[4];
    int lane = threadIdx.x & 63, wid = threadIdx.x >> 6;
    if (lane == 0) wsum[wid] = acc;
    __syncthreads();
    if (threadIdx.x == 0)
        partials[blockIdx.x] = wsum[0] + wsum[1] + wsum[2] + wsum[3];
}

__global__ __launch_bounds__(256) void scloss_final(
    const float* __restrict__ partials, int n, float* __restrict__ out)
{
    double a = 0.0;
    for (int i = threadIdx.x; i < n; i += 256) a += (double)partials[i];
    __shared__ double sd[256];
    sd[threadIdx.x] = a;
    __syncthreads();
    for (int s = 128; s > 0; s >>= 1) {
        if (threadIdx.x < s) sd[threadIdx.x] += sd[threadIdx.x + s];
        __syncthreads();
    }
    if (threadIdx.x == 0) out[0] = (float)(sd[0] / N_MEAN);
}

extern "C" void kernel_launch(void* const* d_in, const int* in_sizes, int n_in,
                              void* d_out, int out_size, void* d_ws, size_t ws_size,
                              hipStream_t stream) {
    const float* cmap = (const float*)d_in[0];
    const int*   tgt  = (const int*)d_in[1];
    float* out      = (float*)d_out;
    float* partials = (float*)d_ws;

    scloss_main<<<NBLK, 256, 0, stream>>>(cmap, tgt, partials);
    scloss_final<<<1, 256, 0, stream>>>(partials, NBLK, out);
}

// Round 11
// 24.647 us; speedup vs baseline: 1.0496x; 1.0496x over previous
//
#include <hip/hip_runtime.h>

#define IMG_H 512
#define IMG_W 512
#define NB    8
#define TILE  32
#define LROWS 34            // owner rows 0..31 + 2 halo rows below
#define LCOLS 36            // owner col j -> lds col j+2 (halo +-2)
#define NBLK  (NB * (IMG_H / TILE) * (IMG_W / TILE))   // 2048
#define N_MEAN 16777216.0   // B * 8 dirs * H * W
#define LOG2E 1.44269504f
#define LN2   0.69314718f

__device__ __forceinline__ float frcp(float x){ return __builtin_amdgcn_rcpf(x); }
__device__ __forceinline__ float fexp2(float x){ return __builtin_amdgcn_exp2f(x); }
__device__ __forceinline__ float flog2(float x){ return __builtin_amdgcn_logf(x); }

// Pin a float4 into VGPRs NOW (defeats compiler load-sinking / LDS re-reads).
#define PIN4(v) asm volatile("" : "+v"(v.x), "+v"(v.y), "+v"(v.z), "+v"(v.w))

// Per-pixel pack {s, mw, e', nw}:
//   s  = sigmoid(c_map)
//   mw = (t ? -0.6 : -1.4) * log(sel+1e-4), sel = t ? s : 1-s   (eq-pair num, K=1 weight)
//   e' = (t ? -1 : +1) * exp(-s);  e' == 0  => OOB sentinel
//   nw = (t ? -0.07 : -0.28) * log(sel+1e-4)                    (nbr num, -0.35*k folded)
__global__ __launch_bounds__(256, 6) void scloss_main(
    const float* __restrict__ cmap, const int* __restrict__ tgt,
    float* __restrict__ partials)
{
    __shared__ float4 pack[LROWS * LCOLS];

    const int tilesPerRow = IMG_W / TILE;                 // 16
    const int tilesPerImg = (IMG_H / TILE) * tilesPerRow; // 256
    int blk = blockIdx.x;
    int b   = blk / tilesPerImg;
    int ti  = blk % tilesPerImg;
    int tr  = (ti / tilesPerRow) * TILE;
    int tc  = (ti % tilesPerRow) * TILE;

    const float* cimg = cmap + (size_t)b * (IMG_H * IMG_W);
    const int*   timg = tgt  + (size_t)b * (IMG_H * IMG_W);

    // Stage rows tr..tr+33, cols tc-2..tc+33.
    for (int idx = threadIdx.x; idx < LROWS * LCOLS; idx += 256) {
        int lr = idx / LCOLS, lc = idx - lr * LCOLS;
        int gr = tr + lr, gc = tc + lc - 2;
        float4 v = make_float4(0.0f, 0.0f, 0.0f, 0.0f);
        if (gr < IMG_H && (unsigned)gc < (unsigned)IMG_W) {
            float x = cimg[gr * IMG_W + gc];
            bool  t = timg[gr * IMG_W + gc] != 0;
            float s   = frcp(1.0f + fexp2(x * -LOG2E));
            float sel = t ? s : (1.0f - s);
            float L   = LN2 * flog2(sel + 1e-4f);
            float e   = fexp2(s * -LOG2E);
            v = make_float4(s,
                            (t ? -0.6f : -1.4f) * L,
                            t ? -e : e,
                            (t ? -0.07f : -0.28f) * L);
        }
        pack[idx] = v;
    }
    __syncthreads();

    int j  = threadIdx.x & 31;
    int i0 = threadIdx.x >> 5;      // 0..7 -> owner rows 4*i0..4*i0+3
    float acc = 0.0f;

// One edge on a pre-loaded (pinned) neighbor float4, named-scalar outputs.
#define EDGE(VB, Dd, Nn, WSK, MK) do {                                    \
        float4 vb  = (VB);                                                \
        bool  tb   = vb.z < 0.0f;                                         \
        bool  qpos = (ta == tb);           /* both targets equal */       \
        bool  qnz  = vb.z != 0.0f;         /* neighbor in bounds */       \
        float ppp  = __builtin_fmaf(sa, vb.x, 1e-4f);                     \
        float ompp = __builtin_fmaf(-sa, vb.x, 1.0001f);                  \
        float argc = (qpos && ta) ? ppp : ompp;                           \
        float lg   = flog2(argc);                                         \
        float E    = fexp2(__builtin_fmaf(ppp, -LOG2E, 1e-4f * LOG2E));   \
        float een  = ta ? vb.z : epa;      /* e' of the t=0 endpoint */   \
        float ee   = qpos ? E : een;                                      \
        Dd         = __builtin_fmaf(-LN2, lg, ee);                        \
        float nm   = qpos ? __builtin_fmaf(WSK, vb.y, MK) : (nwa + vb.w); \
        Nn         = qnz ? nm : 0.0f;                                     \
    } while (0)

// 4 divisions with one reciprocal.
#define COMBINE do {                                                      \
        float d01 = D0 * D1, d23 = D2 * D3;                               \
        float R   = frcp(d01 * d23);                                      \
        float n01 = __builtin_fmaf(N1, D0, N0 * D1);                      \
        float n23 = __builtin_fmaf(N3, D2, N2 * D3);                      \
        acc = __builtin_fmaf(__builtin_fmaf(n23, d01, n01 * d23), R, acc);\
    } while (0)

// One pixel: hoist + PIN all 8 neighbor loads (forces 8 ds_read_b128 issued
// up front, results resident in VGPRs), THEN the math.
#define PIXEL(VA, S1X, S2X, base) do {                                    \
        float4 va_  = (VA);                                               \
        float4 nE1  = base[1],         nE2  = base[2];                    \
        float4 nSE1 = base[LCOLS + 1], nSE2 = base[2*LCOLS + 2];          \
        float4 nSW1 = base[LCOLS - 1], nSW2 = base[2*LCOLS - 2];          \
        float4 nS1  = (S1X),           nS2  = (S2X);                      \
        PIN4(nE1);  PIN4(nE2);  PIN4(nSE1); PIN4(nSE2);                   \
        PIN4(nSW1); PIN4(nSW2); PIN4(nS1);  PIN4(nS2);                    \
        bool  ta  = va_.z < 0.0f;                                         \
        float sa  = va_.x, nwa = va_.w, epa = va_.z;                      \
        float mwa = va_.y, hmw = 0.5f * va_.y;                            \
        float D0, D1, D2, D3, N0, N1, N2, N3;                             \
        EDGE(nE1,  D0, N0, 1.0f, mwa);   /* E  K1 */                      \
        EDGE(nSE1, D1, N1, 1.0f, mwa);   /* SE K1 */                      \
        EDGE(nS1,  D2, N2, 1.0f, mwa);   /* S  K1 */                      \
        EDGE(nSW1, D3, N3, 1.0f, mwa);   /* SW K1 */                      \
        COMBINE;                                                          \
        EDGE(nE2,  D0, N0, 0.5f, hmw);   /* E  K2 */                      \
        EDGE(nSE2, D1, N1, 0.5f, hmw);   /* SE K2 */                      \
        EDGE(nS2,  D2, N2, 0.5f, hmw);   /* S  K2 */                      \
        EDGE(nSW2, D3, N3, 0.5f, hmw);   /* SW K2 */                      \
        COMBINE;                                                          \
    } while (0)

    {
        const float4* b0 = &pack[(i0 * 4) * LCOLS + (j + 2)];
        const float4* b1 = b0 + LCOLS;
        const float4* b2 = b1 + LCOLS;
        const float4* b3 = b2 + LCOLS;
        float4 va0 = b0[0], va1 = b1[0], va2 = b2[0], va3 = b3[0];
        PIXEL(va0, va1, va2,                  b0);
        PIXEL(va1, va2, va3,                  b1);
        PIXEL(va2, va3, b2[2 * LCOLS],        b2);
        PIXEL(va3, b3[LCOLS], b3[2 * LCOLS],  b3);
    }
#undef PIXEL
#undef COMBINE
#undef EDGE

    // Block reduction: wave64 shuffle then cross-wave via LDS.
    #pragma unroll
    for (int o = 32; o > 0; o >>= 1) acc += __shfl_down(acc, o, 64);
    __shared__ float wsum[4];
    int lane = threadIdx.x & 63, wid = threadIdx.x >> 6;
    if (lane == 0) wsum[wid] = acc;
    __syncthreads();
    if (threadIdx.x == 0)
        partials[blockIdx.x] = wsum[0] + wsum[1] + wsum[2] + wsum[3];
}

__global__ __launch_bounds__(256) void scloss_final(
    const float* __restrict__ partials, int n, float* __restrict__ out)
{
    double a = 0.0;
    for (int i = threadIdx.x; i < n; i += 256) a += (double)partials[i];
    __shared__ double sd[256];
    sd[threadIdx.x] = a;
    __syncthreads();
    for (int s = 128; s > 0; s >>= 1) {
        if (threadIdx.x < s) sd[threadIdx.x] += sd[threadIdx.x + s];
        __syncthreads();
    }
    if (threadIdx.x == 0) out[0] = (float)(sd[0] / N_MEAN);
}

extern "C" void kernel_launch(void* const* d_in, const int* in_sizes, int n_in,
                              void* d_out, int out_size, void* d_ws, size_t ws_size,
                              hipStream_t stream) {
    const float* cmap = (const float*)d_in[0];
    const int*   tgt  = (const int*)d_in[1];
    float* out      = (float*)d_out;
    float* partials = (float*)d_ws;

    scloss_main<<<NBLK, 256, 0, stream>>>(cmap, tgt, partials);
    scloss_final<<<1, 256, 0, stream>>>(partials, NBLK, out);
}